// Round 9
// baseline (205.918 us; speedup 1.0000x reference)
//
#include <hip/hip_runtime.h>
#include <hip/hip_fp16.h>

#define S_LEN 1024
#define BATCH 4096
#define HID   4

// chunked-scan parameters: 16 chunks of 64 core steps, 64-step warmup.
#define NCHUNK 16
#define CORE   64
#define WARM   64

// P (prepped params) layout in floats
#define P_WC  0    // 32: combined obs->z weights [8][4]
#define P_BC  32   // 4 : combined bias
#define P_WIH 36   // 64: pre-scaled W_ih [16][4]
#define P_WHH 100  // 64: pre-scaled W_hh [16][4]
#define P_BS  164  // 16: pre-scaled b_ih+b_hh
#define P_TOT 180

#define L2E  1.4426950408889634f
#define L2E2 2.8853900817779268f

typedef float    f4v __attribute__((ext_vector_type(4)));
typedef unsigned u2v __attribute__((ext_vector_type(2)));

__device__ __forceinline__ float fexp2(float x) { return __builtin_amdgcn_exp2f(x); }
__device__ __forceinline__ float frcp(float x)  { return __builtin_amdgcn_rcpf(x); }
__device__ __forceinline__ float frsq(float x)  { return __builtin_amdgcn_rsqf(x); }

// fp16 pack/unpack (RNE)
__device__ __forceinline__ unsigned f2h(float f) {
    return (unsigned)__half_as_ushort(__float2half_rn(f));
}
__device__ __forceinline__ float h2f(unsigned u) {
    return __half2float(__ushort_as_half((unsigned short)(u & 0xFFFFu)));
}

// quad_perm DPP: xor1 = [1,0,3,2] = 0xB1 ; xor2 = [2,3,0,1] = 0x4E
#define DPP_XOR1(x) __int_as_float(__builtin_amdgcn_mov_dpp(__float_as_int(x), 0xB1, 0xF, 0xF, true))
#define DPP_XOR2(x) __int_as_float(__builtin_amdgcn_mov_dpp(__float_as_int(x), 0x4E, 0xF, 0xF, true))

// ---------------- K0: parameter prep (tiny) ----------------
__global__ void k0_prep(const float* __restrict__ W_obs, const float* __restrict__ b_obs,
                        const float* __restrict__ W_in,  const float* __restrict__ b_in,
                        const float* __restrict__ W_ih,  const float* __restrict__ W_hh,
                        const float* __restrict__ b_ih,  const float* __restrict__ b_hh,
                        float* __restrict__ P)
{
    int tid = threadIdx.x;
    if (tid < 32) {
        int r = tid >> 2, hh = tid & 3;
        float s = 0.f;
        for (int o = 0; o < 8; ++o) s += W_obs[r*8+o] * W_in[o*4+hh];
        P[P_WC + tid] = s;
    } else if (tid < 36) {
        int hh = tid - 32;
        float s = b_in[hh];
        for (int o = 0; o < 8; ++o) s += b_obs[o] * W_in[o*4+hh];
        P[P_BC + hh] = s;
    } else if (tid < 100) {
        int idx = tid - 36; int n = idx >> 2;
        float sc = (n >= 8 && n < 12) ? -L2E2 : -L2E;
        P[P_WIH + idx] = W_ih[idx] * sc;
    } else if (tid < 164) {
        int idx = tid - 100; int n = idx >> 2;
        float sc = (n >= 8 && n < 12) ? -L2E2 : -L2E;
        P[P_WHH + idx] = W_hh[idx] * sc;
    } else if (tid < 180) {
        int n = tid - 164;
        float sc = (n >= 8 && n < 12) ? -L2E2 : -L2E;
        P[P_BS + n] = (b_ih[n] + b_hh[n]) * sc;
    }
}

// ---------------- KA: stream obs+ts (NT, L3-bypass) -> z (fp16) + partial stats ----------------
// NT loads: obs/ts are single-touch 192 MiB — do NOT allocate them in L3, so
// L3 stays dedicated to the u/h ws buffers (64 MiB, fully resident).
// All 12 loads issued before any consumption (memory barrier pins them);
// launch_bounds(256,4) caps at 128 VGPR so the 12 float4 arrays don't spill.
__global__ __launch_bounds__(256, 4) void kA_zstats(
    const float* __restrict__ obs, const float* __restrict__ ts,
    const float* __restrict__ W_in, const float* __restrict__ P,
    uint2* __restrict__ z, float* __restrict__ part1)
{
    const int b = blockIdx.x;
    const int t = b >> 2, slice = b & 3;
    const int tid = threadIdx.x;

    const f4v* ob = (const f4v*)obs + (size_t)t * BATCH * 2;
    const f4v* tp = (const f4v*)ts  + (size_t)t * BATCH;
    uint2*     zp = z + (size_t)t * BATCH;

    // phase A: issue all 12 independent dwordx4 NT loads
    f4v o0[4], o1[4], tv[4];
    #pragma unroll
    for (int k = 0; k < 4; ++k) {
        int e = slice * 1024 + tid + k * 256;
        o0[k] = __builtin_nontemporal_load(&ob[(size_t)e*2]);
        o1[k] = __builtin_nontemporal_load(&ob[(size_t)e*2 + 1]);
        tv[k] = __builtin_nontemporal_load(&tp[e]);
    }
    asm volatile("" ::: "memory");   // keep loads above all consumption

    float wc[8][4], wt[4][4], bc[4];
    #pragma unroll
    for (int r = 0; r < 8; ++r)
        #pragma unroll
        for (int ch = 0; ch < 4; ++ch) wc[r][ch] = P[P_WC + r*4 + ch];
    #pragma unroll
    for (int r = 0; r < 4; ++r)
        #pragma unroll
        for (int ch = 0; ch < 4; ++ch) wt[r][ch] = W_in[(8+r)*4 + ch];
    #pragma unroll
    for (int ch = 0; ch < 4; ++ch) bc[ch] = P[P_BC + ch];

    // phase B: compute z, pack fp16, store, accumulate stats
    float s1[4] = {0,0,0,0}, s2[4] = {0,0,0,0};
    #pragma unroll
    for (int k = 0; k < 4; ++k) {
        int e = slice * 1024 + tid + k * 256;
        float zz[4];
        #pragma unroll
        for (int ch = 0; ch < 4; ++ch) {
            float v = bc[ch];
            v += o0[k].x*wc[0][ch] + o0[k].y*wc[1][ch] + o0[k].z*wc[2][ch] + o0[k].w*wc[3][ch];
            v += o1[k].x*wc[4][ch] + o1[k].y*wc[5][ch] + o1[k].z*wc[6][ch] + o1[k].w*wc[7][ch];
            v += tv[k].x*wt[0][ch] + tv[k].y*wt[1][ch] + tv[k].z*wt[2][ch] + tv[k].w*wt[3][ch];
            zz[ch] = v;
            s1[ch] += v;
            s2[ch] += v * v;
        }
        uint2 o;
        o.x = f2h(zz[0]) | (f2h(zz[1]) << 16);
        o.y = f2h(zz[2]) | (f2h(zz[3]) << 16);
        zp[e] = o;
    }

    #pragma unroll
    for (int m = 32; m >= 1; m >>= 1) {
        #pragma unroll
        for (int ch = 0; ch < 4; ++ch) {
            s1[ch] += __shfl_xor(s1[ch], m);
            s2[ch] += __shfl_xor(s2[ch], m);
        }
    }
    __shared__ float red[4][8];
    int wv = tid >> 6, ln = tid & 63;
    if (ln == 0) {
        #pragma unroll
        for (int ch = 0; ch < 4; ++ch) { red[wv][ch] = s1[ch]; red[wv][4+ch] = s2[ch]; }
    }
    __syncthreads();
    if (tid < 8)
        part1[(size_t)b * 8 + tid] = red[0][tid] + red[1][tid] + red[2][tid] + red[3][tid];
}

// ---------------- KB: in-place u = relu(alpha*z + beta); derives alpha/beta from part1 ----------------
__global__ __launch_bounds__(256) void kB_apply(uint2* __restrict__ uz,
                                                const float* __restrict__ part1,
                                                const float* __restrict__ bn1_g,
                                                const float* __restrict__ bn1_b)
{
    const int b = blockIdx.x;            // 2048 blocks; t = b>>1
    const int t = b >> 1;
    const int tid = threadIdx.x;

    // finalize bn1 for this t (wave-uniform scalar work, ~40 loads)
    const float* p1 = part1 + (size_t)t * 32;
    float av[4], bv[4];
    #pragma unroll
    for (int ch = 0; ch < 4; ++ch) {
        float a = p1[ch] + p1[8+ch] + p1[16+ch] + p1[24+ch];
        float q = p1[4+ch] + p1[12+ch] + p1[20+ch] + p1[28+ch];
        float mean = a * (1.f / BATCH);
        float var  = q * (1.f / BATCH) - mean * mean;
        float rs = frsq(var + 1e-5f);
        av[ch] = bn1_g[ch] * rs;
        bv[ch] = bn1_b[ch] - av[ch] * mean;
    }

    uint2* zp = uz + (size_t)b * 2048;
    #pragma unroll
    for (int k = 0; k < 8; ++k) {
        int e = tid + k * 256;
        uint2 v = zp[e];
        float z0 = h2f(v.x), z1 = h2f(v.x >> 16), z2 = h2f(v.y), z3 = h2f(v.y >> 16);
        z0 = fmaxf(fmaf(z0, av[0], bv[0]), 0.f);
        z1 = fmaxf(fmaf(z1, av[1], bv[1]), 0.f);
        z2 = fmaxf(fmaf(z2, av[2], bv[2]), 0.f);
        z3 = fmaxf(fmaf(z3, av[3], bv[3]), 0.f);
        v.x = f2h(z0) | (f2h(z1) << 16);
        v.y = f2h(z2) | (f2h(z3) << 16);
        zp[e] = v;
    }
}

// ---------------- K2: chunked LSTM scan, 4 lanes/element, fp16 u in / fp16 h out ----------------
__global__ __launch_bounds__(256, 2) void k2_lstm(const uint2* __restrict__ u,
                                                  unsigned short* __restrict__ hbuf,
                                                  const float* __restrict__ P)
{
    const int tid  = threadIdx.x;
    const int lane = tid & 63;
    const int gw   = blockIdx.x * 4 + (tid >> 6);   // global wave id [0,4096)
    const int cno  = gw & (NCHUNK - 1);             // chunk (wave-uniform)
    const int j    = lane & 3;                      // channel owned by this lane
    const int e    = (gw >> 4) * 16 + (lane >> 2);  // batch element

    const int core0  = cno * CORE;
    const int tstart = cno ? core0 - WARM : 0;
    const int tend   = core0 + CORE;

    const float* Wih = P + P_WIH;
    const float* Whh = P + P_WHH;
    const float* bs  = P + P_BS;

    float wiI[4], wiF[4], wiG[4], wiO[4];
    float whI[4], whF[4], whG[4], whO[4];
    #pragma unroll
    for (int k = 0; k < 4; ++k) {
        wiI[k] = Wih[(0 +j)*4 + k];
        wiF[k] = Wih[(4 +j)*4 + k];
        wiG[k] = Wih[(8 +j)*4 + k];
        wiO[k] = Wih[(12+j)*4 + k];
        int kc = j ^ k;                          // XOR-order to match DPP allgather
        whI[k] = Whh[(0 +j)*4 + kc];
        whF[k] = Whh[(4 +j)*4 + kc];
        whG[k] = Whh[(8 +j)*4 + kc];
        whO[k] = Whh[(12+j)*4 + kc];
    }
    const float bI = bs[j], bF = bs[4+j], bG = bs[8+j], bO = bs[12+j];

    float h[4] = {0.f, 0.f, 0.f, 0.f};          // h[k] = h_{j^k}
    float c = 0.f;

    const uint2* ub = u + e;
    unsigned short* hp = hbuf + (size_t)e * 4 + j;

    auto STEP = [&](uint2 uv, int t) {
        float ua[4] = {h2f(uv.x), h2f(uv.x >> 16), h2f(uv.y), h2f(uv.y >> 16)};
        float Ui = fmaf(ua[3], wiI[3], fmaf(ua[2], wiI[2], fmaf(ua[1], wiI[1], fmaf(ua[0], wiI[0], bI))));
        float Uf = fmaf(ua[3], wiF[3], fmaf(ua[2], wiF[2], fmaf(ua[1], wiF[1], fmaf(ua[0], wiF[0], bF))));
        float Ug = fmaf(ua[3], wiG[3], fmaf(ua[2], wiG[2], fmaf(ua[1], wiG[1], fmaf(ua[0], wiG[0], bG))));
        float Uo = fmaf(ua[3], wiO[3], fmaf(ua[2], wiO[2], fmaf(ua[1], wiO[1], fmaf(ua[0], wiO[0], bO))));
        float hiI = fmaf(h[0], whI[0], h[1]*whI[1]) + fmaf(h[2], whI[2], h[3]*whI[3]);
        float hiF = fmaf(h[0], whF[0], h[1]*whF[1]) + fmaf(h[2], whF[2], h[3]*whF[3]);
        float hiG = fmaf(h[0], whG[0], h[1]*whG[1]) + fmaf(h[2], whG[2], h[3]*whG[3]);
        float hiO = fmaf(h[0], whO[0], h[1]*whO[1]) + fmaf(h[2], whO[2], h[3]*whO[3]);
        float Gi = Ui + hiI, Gf = Uf + hiF, Gg = Ug + hiG, Go = Uo + hiO;
        float pi = fexp2(Gi), pf = fexp2(Gf), qg = fexp2(Gg), po = fexp2(Go);
        float rf  = frcp(1.f + pf);                    // sig(f)
        float rig = frcp((1.f + pi) * (1.f + qg));     // 1/((1+pi)(1+qg))
        c = c * rf + (1.f - qg) * rig;                 // sig(f)*c + sig(i)*tanh(g)
        float qc  = fexp2(-L2E2 * c);
        float rhc = frcp((1.f + po) * (1.f + qc));
        float hj  = (1.f - qc) * rhc;                  // sig(o)*tanh(c)
        float x1 = DPP_XOR1(hj);
        float y0 = DPP_XOR2(hj);
        float y1 = DPP_XOR2(x1);
        h[0] = hj; h[1] = x1; h[2] = y0; h[3] = y1;
        if (t >= core0)
            hp[(size_t)t * (BATCH * HID)] = (unsigned short)f2h(hj);
    };

    uint2 buf[4][4];
    #pragma unroll
    for (int it = 0; it < 4; ++it)
        #pragma unroll
        for (int s = 0; s < 4; ++s)
            buf[it][s] = ub[(size_t)(tstart + it*4 + s) * BATCH];

    for (int t0 = tstart; t0 < tend - 16; t0 += 16) {
        #pragma unroll
        for (int it = 0; it < 4; ++it) {
            const int tb = t0 + it * 4;
            STEP(buf[it][0], tb + 0);
            STEP(buf[it][1], tb + 1);
            STEP(buf[it][2], tb + 2);
            STEP(buf[it][3], tb + 3);
            #pragma unroll
            for (int s = 0; s < 4; ++s)
                buf[it][s] = ub[(size_t)(tb + 16 + s) * BATCH];
        }
    }
    {
        const int t0 = tend - 16;
        #pragma unroll
        for (int it = 0; it < 4; ++it) {
            const int tb = t0 + it * 4;
            STEP(buf[it][0], tb + 0);
            STEP(buf[it][1], tb + 1);
            STEP(buf[it][2], tb + 2);
            STEP(buf[it][3], tb + 3);
        }
    }
}

// ---------------- K3a: h (fp16) partial stats ----------------
__global__ __launch_bounds__(256) void k3a_stats(const uint2* __restrict__ hbuf,
                                                 float* __restrict__ part2)
{
    const int b = blockIdx.x;
    const int t = b >> 2, slice = b & 3;
    const int tid = threadIdx.x;
    const uint2* hp = hbuf + (size_t)t * BATCH;

    uint2 v[4];
    #pragma unroll
    for (int k = 0; k < 4; ++k)
        v[k] = hp[slice * 1024 + tid + k * 256];

    float s1[4] = {0,0,0,0}, s2[4] = {0,0,0,0};
    #pragma unroll
    for (int k = 0; k < 4; ++k) {
        float h0 = h2f(v[k].x), h1 = h2f(v[k].x >> 16), h2 = h2f(v[k].y), h3 = h2f(v[k].y >> 16);
        s1[0] += h0; s1[1] += h1; s1[2] += h2; s1[3] += h3;
        s2[0] += h0*h0; s2[1] += h1*h1; s2[2] += h2*h2; s2[3] += h3*h3;
    }
    #pragma unroll
    for (int m = 32; m >= 1; m >>= 1) {
        #pragma unroll
        for (int ch = 0; ch < 4; ++ch) {
            s1[ch] += __shfl_xor(s1[ch], m);
            s2[ch] += __shfl_xor(s2[ch], m);
        }
    }
    __shared__ float red[4][8];
    int wv = tid >> 6, ln = tid & 63;
    if (ln == 0) {
        #pragma unroll
        for (int ch = 0; ch < 4; ++ch) { red[wv][ch] = s1[ch]; red[wv][4+ch] = s2[ch]; }
    }
    __syncthreads();
    if (tid < 8)
        part2[(size_t)b * 8 + tid] = red[0][tid] + red[1][tid] + red[2][tid] + red[3][tid];
}

// ---------------- K3b: finalize bn2 in-block, y = h @ Wp + bp ; NT in/out ----------------
__global__ __launch_bounds__(512) void k3b_apply(const uint2* __restrict__ hbuf,
                                                 const float* __restrict__ part2,
                                                 const float* __restrict__ bn2_g,
                                                 const float* __restrict__ bn2_b,
                                                 const float* __restrict__ W_out,
                                                 const float* __restrict__ b_out,
                                                 float* __restrict__ out)
{
    const int b = blockIdx.x;            // t*2 + half
    const int t = b >> 1, half = b & 1;
    const int tid = threadIdx.x;

    // finalize bn2 for this t and fold into output weights (wave-uniform)
    const float* p2 = part2 + (size_t)t * 32;
    float a2[4], be2[4];
    #pragma unroll
    for (int ch = 0; ch < 4; ++ch) {
        float a = p2[ch] + p2[8+ch] + p2[16+ch] + p2[24+ch];
        float q = p2[4+ch] + p2[12+ch] + p2[20+ch] + p2[28+ch];
        float mean = a * (1.f / BATCH);
        float var  = q * (1.f / BATCH) - mean * mean;
        float rs = frsq(var + 1e-5f);
        a2[ch]  = bn2_g[ch] * rs;
        be2[ch] = bn2_b[ch] - a2[ch] * mean;
    }
    float4 w[8];
    float bp[8];
    #pragma unroll
    for (int m = 0; m < 8; ++m) bp[m] = b_out[m];
    #pragma unroll
    for (int jc = 0; jc < 4; ++jc) {
        float w0 = W_out[jc*8+0], w1 = W_out[jc*8+1], w2 = W_out[jc*8+2], w3 = W_out[jc*8+3];
        float w4 = W_out[jc*8+4], w5 = W_out[jc*8+5], w6 = W_out[jc*8+6], w7 = W_out[jc*8+7];
        w[2*jc]   = {a2[jc]*w0, a2[jc]*w1, a2[jc]*w2, a2[jc]*w3};
        w[2*jc+1] = {a2[jc]*w4, a2[jc]*w5, a2[jc]*w6, a2[jc]*w7};
        bp[0] += be2[jc]*w0; bp[1] += be2[jc]*w1; bp[2] += be2[jc]*w2; bp[3] += be2[jc]*w3;
        bp[4] += be2[jc]*w4; bp[5] += be2[jc]*w5; bp[6] += be2[jc]*w6; bp[7] += be2[jc]*w7;
    }
    float4 bp0 = {bp[0], bp[1], bp[2], bp[3]};
    float4 bp1 = {bp[4], bp[5], bp[6], bp[7]};

    const uint2* hp = hbuf + (size_t)t * BATCH + half * 2048;
    float4*      op = (float4*)out + ((size_t)t * BATCH + half * 2048) * 2;

    #pragma unroll
    for (int k = 0; k < 4; ++k) {
        int e = tid + k * 512;
        u2v hv = __builtin_nontemporal_load((const u2v*)&hp[e]);   // last touch of h
        float v0 = h2f(hv.x), v1 = h2f(hv.x >> 16), v2 = h2f(hv.y), v3 = h2f(hv.y >> 16);
        float4 y0 = bp0, y1 = bp1;
        y0.x = fmaf(v0, w[0].x, y0.x); y0.y = fmaf(v0, w[0].y, y0.y);
        y0.z = fmaf(v0, w[0].z, y0.z); y0.w = fmaf(v0, w[0].w, y0.w);
        y1.x = fmaf(v0, w[1].x, y1.x); y1.y = fmaf(v0, w[1].y, y1.y);
        y1.z = fmaf(v0, w[1].z, y1.z); y1.w = fmaf(v0, w[1].w, y1.w);
        y0.x = fmaf(v1, w[2].x, y0.x); y0.y = fmaf(v1, w[2].y, y0.y);
        y0.z = fmaf(v1, w[2].z, y0.z); y0.w = fmaf(v1, w[2].w, y0.w);
        y1.x = fmaf(v1, w[3].x, y1.x); y1.y = fmaf(v1, w[3].y, y1.y);
        y1.z = fmaf(v1, w[3].z, y1.z); y1.w = fmaf(v1, w[3].w, y1.w);
        y0.x = fmaf(v2, w[4].x, y0.x); y0.y = fmaf(v2, w[4].y, y0.y);
        y0.z = fmaf(v2, w[4].z, y0.z); y0.w = fmaf(v2, w[4].w, y0.w);
        y1.x = fmaf(v2, w[5].x, y1.x); y1.y = fmaf(v2, w[5].y, y1.y);
        y1.z = fmaf(v2, w[5].z, y1.z); y1.w = fmaf(v2, w[5].w, y1.w);
        y0.x = fmaf(v3, w[6].x, y0.x); y0.y = fmaf(v3, w[6].y, y0.y);
        y0.z = fmaf(v3, w[6].z, y0.z); y0.w = fmaf(v3, w[6].w, y0.w);
        y1.x = fmaf(v3, w[7].x, y1.x); y1.y = fmaf(v3, w[7].y, y1.y);
        y1.z = fmaf(v3, w[7].z, y1.z); y1.w = fmaf(v3, w[7].w, y1.w);
        // non-temporal: out is never re-read; keep it out of L3
        __builtin_nontemporal_store(*(f4v*)&y0, (f4v*)&op[(size_t)e*2]);
        __builtin_nontemporal_store(*(f4v*)&y1, (f4v*)&op[(size_t)e*2 + 1]);
    }
}

extern "C" void kernel_launch(void* const* d_in, const int* in_sizes, int n_in,
                              void* d_out, int out_size, void* d_ws, size_t ws_size,
                              hipStream_t stream)
{
    const float* obs   = (const float*)d_in[0];
    const float* ts    = (const float*)d_in[1];
    const float* W_obs = (const float*)d_in[2];
    const float* b_obs = (const float*)d_in[3];
    const float* W_in  = (const float*)d_in[4];
    const float* b_in  = (const float*)d_in[5];
    const float* bn1_g = (const float*)d_in[6];
    const float* bn1_b = (const float*)d_in[7];
    const float* W_ih  = (const float*)d_in[8];
    const float* W_hh  = (const float*)d_in[9];
    const float* b_ih  = (const float*)d_in[10];
    const float* b_hh  = (const float*)d_in[11];
    const float* bn2_g = (const float*)d_in[12];
    const float* bn2_b = (const float*)d_in[13];
    const float* W_out = (const float*)d_in[14];
    const float* b_out = (const float*)d_in[15];
    float* out = (float*)d_out;

    // ws layout (bytes): u_fp16 [0,32Mi) | h_fp16 [32Mi,64Mi) | P
    // Overlays (time-disjoint): part1 in h region (pre-k2);
    //                           part2 in u region (post-k2).
    char* base = (char*)d_ws;
    uint2*          u16 = (uint2*)base;                                   // S*B uint2 = 32 MiB
    unsigned short* h16 = (unsigned short*)(base + (size_t)32 * 1024 * 1024);
    float*          P   = (float*)(base + (size_t)64 * 1024 * 1024);

    float* part1 = (float*)h16;              // 4096*8 floats (pre-k2 overlay)
    float* part2 = (float*)base;             // 4096*8 floats (post-k2 overlay)

    k0_prep<<<1, 192, 0, stream>>>(W_obs, b_obs, W_in, b_in, W_ih, W_hh, b_ih, b_hh, P);
    kA_zstats<<<S_LEN * 4, 256, 0, stream>>>(obs, ts, W_in, P, u16, part1);
    kB_apply<<<S_LEN * 2, 256, 0, stream>>>(u16, part1, bn1_g, bn1_b);
    k2_lstm<<<(BATCH / 16) * NCHUNK / 4, 256, 0, stream>>>(u16, h16, P);
    k3a_stats<<<S_LEN * 4, 256, 0, stream>>>((const uint2*)h16, part2);
    k3b_apply<<<S_LEN * 2, 512, 0, stream>>>((const uint2*)h16, part2, bn2_g, bn2_b, W_out, b_out, out);
}

// Round 10
// 172.882 us; speedup vs baseline: 1.1911x; 1.1911x over previous
//
#include <hip/hip_runtime.h>
#include <hip/hip_fp16.h>

#define S_LEN 1024
#define BATCH 4096
#define HID   4

// chunked-scan parameters: 8 chunks of 128 core steps, 48-step warmup.
#define NCHUNK 8
#define CORE   128
#define WARM   48

// P (prepped params) layout in floats
#define P_WC   0    // 32: combined obs->z weights [8][4]
#define P_BC   32   // 4 : combined bias
#define P_WIH  36   // 64: pre-scaled W_ih [16][4] (f32, fallback path)
#define P_WHH  100  // 64: pre-scaled W_hh [16][4]
#define P_BS   164  // 16: pre-scaled b_ih+b_hh
#define P_WH2  180  // 32: pre-scaled W_ih as packed fp16 pairs [16 rows][2]
#define P_TOT  212

#define L2E  1.4426950408889634f
#define L2E2 2.8853900817779268f

typedef float    f4v __attribute__((ext_vector_type(4)));
typedef unsigned u2v __attribute__((ext_vector_type(2)));
typedef _Float16 h2v __attribute__((ext_vector_type(2)));

#if defined(__has_builtin)
#if __has_builtin(__builtin_amdgcn_fdot2)
#define HAS_FDOT2 1
#endif
#endif

__device__ __forceinline__ float fexp2(float x) { return __builtin_amdgcn_exp2f(x); }
__device__ __forceinline__ float frcp(float x)  { return __builtin_amdgcn_rcpf(x); }
__device__ __forceinline__ float frsq(float x)  { return __builtin_amdgcn_rsqf(x); }

// fp16 pack/unpack (RNE)
__device__ __forceinline__ unsigned f2h(float f) {
    return (unsigned)__half_as_ushort(__float2half_rn(f));
}
__device__ __forceinline__ float h2f(unsigned u) {
    return __half2float(__ushort_as_half((unsigned short)(u & 0xFFFFu)));
}
__device__ __forceinline__ h2v uash2(unsigned x) {
    union { unsigned u; h2v h; } c; c.u = x; return c.h;
}

// quad_perm DPP: xor1 = [1,0,3,2] = 0xB1 ; xor2 = [2,3,0,1] = 0x4E
#define DPP_XOR1(x) __int_as_float(__builtin_amdgcn_mov_dpp(__float_as_int(x), 0xB1, 0xF, 0xF, true))
#define DPP_XOR2(x) __int_as_float(__builtin_amdgcn_mov_dpp(__float_as_int(x), 0x4E, 0xF, 0xF, true))

// ---------------- K0: parameter prep (tiny) ----------------
__global__ void k0_prep(const float* __restrict__ W_obs, const float* __restrict__ b_obs,
                        const float* __restrict__ W_in,  const float* __restrict__ b_in,
                        const float* __restrict__ W_ih,  const float* __restrict__ W_hh,
                        const float* __restrict__ b_ih,  const float* __restrict__ b_hh,
                        float* __restrict__ P)
{
    int tid = threadIdx.x;
    if (tid < 32) {
        int r = tid >> 2, hh = tid & 3;
        float s = 0.f;
        for (int o = 0; o < 8; ++o) s += W_obs[r*8+o] * W_in[o*4+hh];
        P[P_WC + tid] = s;
    } else if (tid < 36) {
        int hh = tid - 32;
        float s = b_in[hh];
        for (int o = 0; o < 8; ++o) s += b_obs[o] * W_in[o*4+hh];
        P[P_BC + hh] = s;
    } else if (tid < 100) {
        int idx = tid - 36; int n = idx >> 2;
        float sc = (n >= 8 && n < 12) ? -L2E2 : -L2E;
        P[P_WIH + idx] = W_ih[idx] * sc;
    } else if (tid < 164) {
        int idx = tid - 100; int n = idx >> 2;
        float sc = (n >= 8 && n < 12) ? -L2E2 : -L2E;
        P[P_WHH + idx] = W_hh[idx] * sc;
    } else if (tid < 180) {
        int n = tid - 164;
        float sc = (n >= 8 && n < 12) ? -L2E2 : -L2E;
        P[P_BS + n] = (b_ih[n] + b_hh[n]) * sc;
    } else if (tid < 212) {
        // packed fp16 pairs of pre-scaled W_ih: entry = row*2 + p
        int idx = tid - 180; int row = idx >> 1, p = idx & 1;
        float sc = (row >= 8 && row < 12) ? -L2E2 : -L2E;
        float v0 = W_ih[row*4 + 2*p]     * sc;
        float v1 = W_ih[row*4 + 2*p + 1] * sc;
        P[P_WH2 + idx] = __uint_as_float(f2h(v0) | (f2h(v1) << 16));
    }
}

// ---------------- KA: stream obs+ts -> z (fp16) + per-block partial stats ----------------
__global__ __launch_bounds__(256, 4) void kA_zstats(
    const float* __restrict__ obs, const float* __restrict__ ts,
    const float* __restrict__ W_in, const float* __restrict__ P,
    uint2* __restrict__ z, float* __restrict__ part1)
{
    const int b = blockIdx.x;
    const int t = b >> 2, slice = b & 3;
    const int tid = threadIdx.x;

    const float4* ob = (const float4*)obs + (size_t)t * BATCH * 2;
    const float4* tp = (const float4*)ts  + (size_t)t * BATCH;
    uint2*        zp = z + (size_t)t * BATCH;

    // phase A: issue all 12 independent dwordx4 loads
    float4 o0[4], o1[4], tv[4];
    #pragma unroll
    for (int k = 0; k < 4; ++k) {
        int e = slice * 1024 + tid + k * 256;
        o0[k] = ob[(size_t)e*2];
        o1[k] = ob[(size_t)e*2 + 1];
        tv[k] = tp[e];
    }
    asm volatile("" ::: "memory");   // keep loads above all consumption

    float wc[8][4], wt[4][4], bc[4];
    #pragma unroll
    for (int r = 0; r < 8; ++r)
        #pragma unroll
        for (int ch = 0; ch < 4; ++ch) wc[r][ch] = P[P_WC + r*4 + ch];
    #pragma unroll
    for (int r = 0; r < 4; ++r)
        #pragma unroll
        for (int ch = 0; ch < 4; ++ch) wt[r][ch] = W_in[(8+r)*4 + ch];
    #pragma unroll
    for (int ch = 0; ch < 4; ++ch) bc[ch] = P[P_BC + ch];

    // phase B: compute z, pack fp16, store, accumulate stats
    float s1[4] = {0,0,0,0}, s2[4] = {0,0,0,0};
    #pragma unroll
    for (int k = 0; k < 4; ++k) {
        int e = slice * 1024 + tid + k * 256;
        float zz[4];
        #pragma unroll
        for (int ch = 0; ch < 4; ++ch) {
            float v = bc[ch];
            v += o0[k].x*wc[0][ch] + o0[k].y*wc[1][ch] + o0[k].z*wc[2][ch] + o0[k].w*wc[3][ch];
            v += o1[k].x*wc[4][ch] + o1[k].y*wc[5][ch] + o1[k].z*wc[6][ch] + o1[k].w*wc[7][ch];
            v += tv[k].x*wt[0][ch] + tv[k].y*wt[1][ch] + tv[k].z*wt[2][ch] + tv[k].w*wt[3][ch];
            zz[ch] = v;
            s1[ch] += v;
            s2[ch] += v * v;
        }
        uint2 o;
        o.x = f2h(zz[0]) | (f2h(zz[1]) << 16);
        o.y = f2h(zz[2]) | (f2h(zz[3]) << 16);
        zp[e] = o;
    }

    #pragma unroll
    for (int m = 32; m >= 1; m >>= 1) {
        #pragma unroll
        for (int ch = 0; ch < 4; ++ch) {
            s1[ch] += __shfl_xor(s1[ch], m);
            s2[ch] += __shfl_xor(s2[ch], m);
        }
    }
    __shared__ float red[4][8];
    int wv = tid >> 6, ln = tid & 63;
    if (ln == 0) {
        #pragma unroll
        for (int ch = 0; ch < 4; ++ch) { red[wv][ch] = s1[ch]; red[wv][4+ch] = s2[ch]; }
    }
    __syncthreads();
    if (tid < 8)
        part1[(size_t)b * 8 + tid] = red[0][tid] + red[1][tid] + red[2][tid] + red[3][tid];
}

// ---------------- KB: in-place u = relu(alpha*z + beta); derives alpha/beta from part1 ----------------
__global__ __launch_bounds__(256) void kB_apply(uint2* __restrict__ uz,
                                                const float* __restrict__ part1,
                                                const float* __restrict__ bn1_g,
                                                const float* __restrict__ bn1_b)
{
    const int b = blockIdx.x;            // 2048 blocks; t = b>>1
    const int t = b >> 1;
    const int tid = threadIdx.x;

    const float* p1 = part1 + (size_t)t * 32;
    float av[4], bv[4];
    #pragma unroll
    for (int ch = 0; ch < 4; ++ch) {
        float a = p1[ch] + p1[8+ch] + p1[16+ch] + p1[24+ch];
        float q = p1[4+ch] + p1[12+ch] + p1[20+ch] + p1[28+ch];
        float mean = a * (1.f / BATCH);
        float var  = q * (1.f / BATCH) - mean * mean;
        float rs = frsq(var + 1e-5f);
        av[ch] = bn1_g[ch] * rs;
        bv[ch] = bn1_b[ch] - av[ch] * mean;
    }

    uint2* zp = uz + (size_t)b * 2048;
    #pragma unroll
    for (int k = 0; k < 8; ++k) {
        int e = tid + k * 256;
        uint2 v = zp[e];
        float z0 = h2f(v.x), z1 = h2f(v.x >> 16), z2 = h2f(v.y), z3 = h2f(v.y >> 16);
        z0 = fmaxf(fmaf(z0, av[0], bv[0]), 0.f);
        z1 = fmaxf(fmaf(z1, av[1], bv[1]), 0.f);
        z2 = fmaxf(fmaf(z2, av[2], bv[2]), 0.f);
        z3 = fmaxf(fmaf(z3, av[3], bv[3]), 0.f);
        v.x = f2h(z0) | (f2h(z1) << 16);
        v.y = f2h(z2) | (f2h(z3) << 16);
        zp[e] = v;
    }
}

// ---------------- K2: chunked LSTM scan, 4 lanes/element, fp16 u via v_dot2 ----------------
// NCHUNK=8 (2048 waves, 2/SIMD), WARM=48 (3x16-step groups, no stores/predicate),
// CORE=128. u-MACs: 8x v_dot2_f32_f16 instead of 4 cvt + 16 fma.
__global__ __launch_bounds__(256, 2) void k2_lstm(const uint2* __restrict__ u,
                                                  unsigned short* __restrict__ hbuf,
                                                  const float* __restrict__ P)
{
    const int tid  = threadIdx.x;
    const int lane = tid & 63;
    const int gw   = blockIdx.x * 4 + (tid >> 6);   // global wave id [0,2048)
    const int cno  = gw & (NCHUNK - 1);             // chunk (wave-uniform)
    const int j    = lane & 3;                      // channel owned by this lane
    const int e    = (gw >> 3) * 16 + (lane >> 2);  // batch element

    const int core0  = cno * CORE;
    const int tstart = cno ? core0 - WARM : 0;
    const int tend   = core0 + CORE;

    const float* Whh = P + P_WHH;
    const float* bs  = P + P_BS;

#ifdef HAS_FDOT2
    unsigned wI0 = __float_as_uint(P[P_WH2 + (0 +j)*2]);
    unsigned wI1 = __float_as_uint(P[P_WH2 + (0 +j)*2 + 1]);
    unsigned wF0 = __float_as_uint(P[P_WH2 + (4 +j)*2]);
    unsigned wF1 = __float_as_uint(P[P_WH2 + (4 +j)*2 + 1]);
    unsigned wG0 = __float_as_uint(P[P_WH2 + (8 +j)*2]);
    unsigned wG1 = __float_as_uint(P[P_WH2 + (8 +j)*2 + 1]);
    unsigned wO0 = __float_as_uint(P[P_WH2 + (12+j)*2]);
    unsigned wO1 = __float_as_uint(P[P_WH2 + (12+j)*2 + 1]);
#else
    const float* Wih = P + P_WIH;
    float wiI[4], wiF[4], wiG[4], wiO[4];
    #pragma unroll
    for (int k = 0; k < 4; ++k) {
        wiI[k] = Wih[(0 +j)*4 + k];
        wiF[k] = Wih[(4 +j)*4 + k];
        wiG[k] = Wih[(8 +j)*4 + k];
        wiO[k] = Wih[(12+j)*4 + k];
    }
#endif
    float whI[4], whF[4], whG[4], whO[4];
    #pragma unroll
    for (int k = 0; k < 4; ++k) {
        int kc = j ^ k;                          // XOR-order to match DPP allgather
        whI[k] = Whh[(0 +j)*4 + kc];
        whF[k] = Whh[(4 +j)*4 + kc];
        whG[k] = Whh[(8 +j)*4 + kc];
        whO[k] = Whh[(12+j)*4 + kc];
    }
    const float bI = bs[j], bF = bs[4+j], bG = bs[8+j], bO = bs[12+j];

    float h[4] = {0.f, 0.f, 0.f, 0.f};          // h[k] = h_{j^k}
    float c = 0.f;

    const uint2* ub = u + e;
    unsigned short* hp = hbuf + (size_t)e * 4 + j;

    auto STEP = [&](uint2 uv, int t, bool store) {
#ifdef HAS_FDOT2
        float Ui = __builtin_amdgcn_fdot2(uash2(uv.x), uash2(wI0),
                   __builtin_amdgcn_fdot2(uash2(uv.y), uash2(wI1), bI, false), false);
        float Uf = __builtin_amdgcn_fdot2(uash2(uv.x), uash2(wF0),
                   __builtin_amdgcn_fdot2(uash2(uv.y), uash2(wF1), bF, false), false);
        float Ug = __builtin_amdgcn_fdot2(uash2(uv.x), uash2(wG0),
                   __builtin_amdgcn_fdot2(uash2(uv.y), uash2(wG1), bG, false), false);
        float Uo = __builtin_amdgcn_fdot2(uash2(uv.x), uash2(wO0),
                   __builtin_amdgcn_fdot2(uash2(uv.y), uash2(wO1), bO, false), false);
#else
        float ua[4] = {h2f(uv.x), h2f(uv.x >> 16), h2f(uv.y), h2f(uv.y >> 16)};
        float Ui = fmaf(ua[3], wiI[3], fmaf(ua[2], wiI[2], fmaf(ua[1], wiI[1], fmaf(ua[0], wiI[0], bI))));
        float Uf = fmaf(ua[3], wiF[3], fmaf(ua[2], wiF[2], fmaf(ua[1], wiF[1], fmaf(ua[0], wiF[0], bF))));
        float Ug = fmaf(ua[3], wiG[3], fmaf(ua[2], wiG[2], fmaf(ua[1], wiG[1], fmaf(ua[0], wiG[0], bG))));
        float Uo = fmaf(ua[3], wiO[3], fmaf(ua[2], wiO[2], fmaf(ua[1], wiO[1], fmaf(ua[0], wiO[0], bO))));
#endif
        float hiI = fmaf(h[0], whI[0], h[1]*whI[1]) + fmaf(h[2], whI[2], h[3]*whI[3]);
        float hiF = fmaf(h[0], whF[0], h[1]*whF[1]) + fmaf(h[2], whF[2], h[3]*whF[3]);
        float hiG = fmaf(h[0], whG[0], h[1]*whG[1]) + fmaf(h[2], whG[2], h[3]*whG[3]);
        float hiO = fmaf(h[0], whO[0], h[1]*whO[1]) + fmaf(h[2], whO[2], h[3]*whO[3]);
        float Gi = Ui + hiI, Gf = Uf + hiF, Gg = Ug + hiG, Go = Uo + hiO;
        float pi = fexp2(Gi), pf = fexp2(Gf), qg = fexp2(Gg), po = fexp2(Go);
        float rf  = frcp(1.f + pf);                    // sig(f)
        float rig = frcp((1.f + pi) * (1.f + qg));     // 1/((1+pi)(1+qg))
        c = c * rf + (1.f - qg) * rig;                 // sig(f)*c + sig(i)*tanh(g)
        float qc  = fexp2(-L2E2 * c);
        float rhc = frcp((1.f + po) * (1.f + qc));
        float hj  = (1.f - qc) * rhc;                  // sig(o)*tanh(c)
        float x1 = DPP_XOR1(hj);
        float y0 = DPP_XOR2(hj);
        float y1 = DPP_XOR2(x1);
        h[0] = hj; h[1] = x1; h[2] = y0; h[3] = y1;
        if (store)
            hp[(size_t)t * (BATCH * HID)] = (unsigned short)f2h(hj);
    };

    uint2 buf[4][4];
    #pragma unroll
    for (int it = 0; it < 4; ++it)
        #pragma unroll
        for (int s = 0; s < 4; ++s)
            buf[it][s] = ub[(size_t)(tstart + it*4 + s) * BATCH];

    // warmup: no stores (48 = 3 groups of 16; absent for chunk 0)
    for (int t0 = tstart; t0 < core0; t0 += 16) {
        #pragma unroll
        for (int it = 0; it < 4; ++it) {
            const int tb = t0 + it * 4;
            STEP(buf[it][0], tb + 0, false);
            STEP(buf[it][1], tb + 1, false);
            STEP(buf[it][2], tb + 2, false);
            STEP(buf[it][3], tb + 3, false);
            #pragma unroll
            for (int s = 0; s < 4; ++s)
                buf[it][s] = ub[(size_t)(tb + 16 + s) * BATCH];
        }
    }
    // core: stores, with refill
    for (int t0 = core0; t0 < tend - 16; t0 += 16) {
        #pragma unroll
        for (int it = 0; it < 4; ++it) {
            const int tb = t0 + it * 4;
            STEP(buf[it][0], tb + 0, true);
            STEP(buf[it][1], tb + 1, true);
            STEP(buf[it][2], tb + 2, true);
            STEP(buf[it][3], tb + 3, true);
            #pragma unroll
            for (int s = 0; s < 4; ++s)
                buf[it][s] = ub[(size_t)(tb + 16 + s) * BATCH];
        }
    }
    { // epilogue: last 16 steps, stores, no refill
        const int t0 = tend - 16;
        #pragma unroll
        for (int it = 0; it < 4; ++it) {
            const int tb = t0 + it * 4;
            STEP(buf[it][0], tb + 0, true);
            STEP(buf[it][1], tb + 1, true);
            STEP(buf[it][2], tb + 2, true);
            STEP(buf[it][3], tb + 3, true);
        }
    }
}

// ---------------- K3a: h (fp16) partial stats ----------------
__global__ __launch_bounds__(256) void k3a_stats(const uint2* __restrict__ hbuf,
                                                 float* __restrict__ part2)
{
    const int b = blockIdx.x;
    const int t = b >> 2, slice = b & 3;
    const int tid = threadIdx.x;
    const uint2* hp = hbuf + (size_t)t * BATCH;

    uint2 v[4];
    #pragma unroll
    for (int k = 0; k < 4; ++k)
        v[k] = hp[slice * 1024 + tid + k * 256];

    float s1[4] = {0,0,0,0}, s2[4] = {0,0,0,0};
    #pragma unroll
    for (int k = 0; k < 4; ++k) {
        float h0 = h2f(v[k].x), h1 = h2f(v[k].x >> 16), h2 = h2f(v[k].y), h3 = h2f(v[k].y >> 16);
        s1[0] += h0; s1[1] += h1; s1[2] += h2; s1[3] += h3;
        s2[0] += h0*h0; s2[1] += h1*h1; s2[2] += h2*h2; s2[3] += h3*h3;
    }
    #pragma unroll
    for (int m = 32; m >= 1; m >>= 1) {
        #pragma unroll
        for (int ch = 0; ch < 4; ++ch) {
            s1[ch] += __shfl_xor(s1[ch], m);
            s2[ch] += __shfl_xor(s2[ch], m);
        }
    }
    __shared__ float red[4][8];
    int wv = tid >> 6, ln = tid & 63;
    if (ln == 0) {
        #pragma unroll
        for (int ch = 0; ch < 4; ++ch) { red[wv][ch] = s1[ch]; red[wv][4+ch] = s2[ch]; }
    }
    __syncthreads();
    if (tid < 8)
        part2[(size_t)b * 8 + tid] = red[0][tid] + red[1][tid] + red[2][tid] + red[3][tid];
}

// ---------------- K3b: finalize bn2 in-block, y = h @ Wp + bp ; NT out ----------------
__global__ __launch_bounds__(512) void k3b_apply(const uint2* __restrict__ hbuf,
                                                 const float* __restrict__ part2,
                                                 const float* __restrict__ bn2_g,
                                                 const float* __restrict__ bn2_b,
                                                 const float* __restrict__ W_out,
                                                 const float* __restrict__ b_out,
                                                 float* __restrict__ out)
{
    const int b = blockIdx.x;            // t*2 + half
    const int t = b >> 1, half = b & 1;
    const int tid = threadIdx.x;

    const float* p2 = part2 + (size_t)t * 32;
    float a2[4], be2[4];
    #pragma unroll
    for (int ch = 0; ch < 4; ++ch) {
        float a = p2[ch] + p2[8+ch] + p2[16+ch] + p2[24+ch];
        float q = p2[4+ch] + p2[12+ch] + p2[20+ch] + p2[28+ch];
        float mean = a * (1.f / BATCH);
        float var  = q * (1.f / BATCH) - mean * mean;
        float rs = frsq(var + 1e-5f);
        a2[ch]  = bn2_g[ch] * rs;
        be2[ch] = bn2_b[ch] - a2[ch] * mean;
    }
    float4 w[8];
    float bp[8];
    #pragma unroll
    for (int m = 0; m < 8; ++m) bp[m] = b_out[m];
    #pragma unroll
    for (int jc = 0; jc < 4; ++jc) {
        float w0 = W_out[jc*8+0], w1 = W_out[jc*8+1], w2 = W_out[jc*8+2], w3 = W_out[jc*8+3];
        float w4 = W_out[jc*8+4], w5 = W_out[jc*8+5], w6 = W_out[jc*8+6], w7 = W_out[jc*8+7];
        w[2*jc]   = {a2[jc]*w0, a2[jc]*w1, a2[jc]*w2, a2[jc]*w3};
        w[2*jc+1] = {a2[jc]*w4, a2[jc]*w5, a2[jc]*w6, a2[jc]*w7};
        bp[0] += be2[jc]*w0; bp[1] += be2[jc]*w1; bp[2] += be2[jc]*w2; bp[3] += be2[jc]*w3;
        bp[4] += be2[jc]*w4; bp[5] += be2[jc]*w5; bp[6] += be2[jc]*w6; bp[7] += be2[jc]*w7;
    }
    float4 bp0 = {bp[0], bp[1], bp[2], bp[3]};
    float4 bp1 = {bp[4], bp[5], bp[6], bp[7]};

    const uint2* hp = hbuf + (size_t)t * BATCH + half * 2048;
    float4*      op = (float4*)out + ((size_t)t * BATCH + half * 2048) * 2;

    #pragma unroll
    for (int k = 0; k < 4; ++k) {
        int e = tid + k * 512;
        u2v hv = __builtin_nontemporal_load((const u2v*)&hp[e]);
        float v0 = h2f(hv.x), v1 = h2f(hv.x >> 16), v2 = h2f(hv.y), v3 = h2f(hv.y >> 16);
        float4 y0 = bp0, y1 = bp1;
        y0.x = fmaf(v0, w[0].x, y0.x); y0.y = fmaf(v0, w[0].y, y0.y);
        y0.z = fmaf(v0, w[0].z, y0.z); y0.w = fmaf(v0, w[0].w, y0.w);
        y1.x = fmaf(v0, w[1].x, y1.x); y1.y = fmaf(v0, w[1].y, y1.y);
        y1.z = fmaf(v0, w[1].z, y1.z); y1.w = fmaf(v0, w[1].w, y1.w);
        y0.x = fmaf(v1, w[2].x, y0.x); y0.y = fmaf(v1, w[2].y, y0.y);
        y0.z = fmaf(v1, w[2].z, y0.z); y0.w = fmaf(v1, w[2].w, y0.w);
        y1.x = fmaf(v1, w[3].x, y1.x); y1.y = fmaf(v1, w[3].y, y1.y);
        y1.z = fmaf(v1, w[3].z, y1.z); y1.w = fmaf(v1, w[3].w, y1.w);
        y0.x = fmaf(v2, w[4].x, y0.x); y0.y = fmaf(v2, w[4].y, y0.y);
        y0.z = fmaf(v2, w[4].z, y0.z); y0.w = fmaf(v2, w[4].w, y0.w);
        y1.x = fmaf(v2, w[5].x, y1.x); y1.y = fmaf(v2, w[5].y, y1.y);
        y1.z = fmaf(v2, w[5].z, y1.z); y1.w = fmaf(v2, w[5].w, y1.w);
        y0.x = fmaf(v3, w[6].x, y0.x); y0.y = fmaf(v3, w[6].y, y0.y);
        y0.z = fmaf(v3, w[6].z, y0.z); y0.w = fmaf(v3, w[6].w, y0.w);
        y1.x = fmaf(v3, w[7].x, y1.x); y1.y = fmaf(v3, w[7].y, y1.y);
        y1.z = fmaf(v3, w[7].z, y1.z); y1.w = fmaf(v3, w[7].w, y1.w);
        __builtin_nontemporal_store(*(f4v*)&y0, (f4v*)&op[(size_t)e*2]);
        __builtin_nontemporal_store(*(f4v*)&y1, (f4v*)&op[(size_t)e*2 + 1]);
    }
}

extern "C" void kernel_launch(void* const* d_in, const int* in_sizes, int n_in,
                              void* d_out, int out_size, void* d_ws, size_t ws_size,
                              hipStream_t stream)
{
    const float* obs   = (const float*)d_in[0];
    const float* ts    = (const float*)d_in[1];
    const float* W_obs = (const float*)d_in[2];
    const float* b_obs = (const float*)d_in[3];
    const float* W_in  = (const float*)d_in[4];
    const float* b_in  = (const float*)d_in[5];
    const float* bn1_g = (const float*)d_in[6];
    const float* bn1_b = (const float*)d_in[7];
    const float* W_ih  = (const float*)d_in[8];
    const float* W_hh  = (const float*)d_in[9];
    const float* b_ih  = (const float*)d_in[10];
    const float* b_hh  = (const float*)d_in[11];
    const float* bn2_g = (const float*)d_in[12];
    const float* bn2_b = (const float*)d_in[13];
    const float* W_out = (const float*)d_in[14];
    const float* b_out = (const float*)d_in[15];
    float* out = (float*)d_out;

    // ws layout (bytes): u_fp16 [0,32Mi) | h_fp16 [32Mi,64Mi) | P
    // Overlays (time-disjoint): part1 in h region (pre-k2);
    //                           part2 in u region (post-k2).
    char* base = (char*)d_ws;
    uint2*          u16 = (uint2*)base;                                   // S*B uint2 = 32 MiB
    unsigned short* h16 = (unsigned short*)(base + (size_t)32 * 1024 * 1024);
    float*          P   = (float*)(base + (size_t)64 * 1024 * 1024);

    float* part1 = (float*)h16;              // 4096*8 floats (pre-k2 overlay)
    float* part2 = (float*)base;             // 4096*8 floats (post-k2 overlay)

    k0_prep<<<1, 256, 0, stream>>>(W_obs, b_obs, W_in, b_in, W_ih, W_hh, b_ih, b_hh, P);
    kA_zstats<<<S_LEN * 4, 256, 0, stream>>>(obs, ts, W_in, P, u16, part1);
    kB_apply<<<S_LEN * 2, 256, 0, stream>>>(u16, part1, bn1_g, bn1_b);
    k2_lstm<<<(BATCH / 16) * NCHUNK / 4, 256, 0, stream>>>(u16, h16, P);
    k3a_stats<<<S_LEN * 4, 256, 0, stream>>>((const uint2*)h16, part2);
    k3b_apply<<<S_LEN * 2, 512, 0, stream>>>((const uint2*)h16, part2, bn2_g, bn2_b, W_out, b_out, out);
}